// Round 9
// baseline (4032.339 us; speedup 1.0000x reference)
//
#include <hip/hip_runtime.h>

#define NPIX 250000
#define NSUP 50000
#define NE   800000
#define DD   128
#define NL   5

#define BN_EPS_C 1e-5f
#define SLOPE 0.01f
#define INV_C (1.0f / 2.9f)

// edge capacity with per-row pad to multiple of 4
#define NEPAD4 (NE + 3 * NSUP)
#define SCAN_PER 52
#define CNT_CAP (1024 * SCAN_PER)

typedef __attribute__((ext_vector_type(8))) short short8v;   // 8 bf16 (4 VGPR)
typedef __attribute__((ext_vector_type(4))) float f32x4;     // MFMA acc

__device__ __forceinline__ size_t rowoff(int r) { return (size_t)r * DD; }

__device__ __forceinline__ unsigned short f2bf(float f) {
    unsigned int u = __float_as_uint(f);
    unsigned int r = (u + 0x7FFFu + ((u >> 16) & 1u)) >> 16;
    return (unsigned short)r;
}
__device__ __forceinline__ float bf2f_lo(unsigned int v) { return __uint_as_float(v << 16); }
__device__ __forceinline__ float bf2f_hi(unsigned int v) { return __uint_as_float(v & 0xFFFF0000u); }
__device__ __forceinline__ float lrelu(float o) { return o > 0.f ? o : SLOPE * o; }

// ---------------- generic histogram ----------------
__global__ __launch_bounds__(256) void hist_k(const int* __restrict__ ids,
        int* __restrict__ cnt, int n) {
    int e = blockIdx.x * 256 + threadIdx.x;
    if (e >= n) return;
    atomicAdd(cnt + ids[e], 1);
}

// ---------------- single-block scan over padded counters ----------------
template <int PAD>
__global__ __launch_bounds__(1024) void scan_rowptr(const int* __restrict__ cnt,
        int* __restrict__ rp) {
    const int t = threadIdx.x;
    const int lo = t * SCAN_PER;
    int4 c[SCAN_PER / 4];
    int s = 0;
    #pragma unroll
    for (int k = 0; k < SCAN_PER / 4; ++k) {
        int4 v = *(const int4*)(cnt + lo + k * 4);
        if (PAD > 1) {
            v.x = (v.x + PAD - 1) & ~(PAD - 1);
            v.y = (v.y + PAD - 1) & ~(PAD - 1);
            v.z = (v.z + PAD - 1) & ~(PAD - 1);
            v.w = (v.w + PAD - 1) & ~(PAD - 1);
        }
        c[k] = v;
        s += v.x + v.y + v.z + v.w;
    }
    int lane = t & 63, wid = t >> 6;
    int v = s;
    #pragma unroll
    for (int d = 1; d < 64; d <<= 1) {
        int u = __shfl_up(v, d);
        if (lane >= d) v += u;
    }
    __shared__ int wtot[16], woff[16];
    if (lane == 63) wtot[wid] = v;
    __syncthreads();
    if (t == 0) {
        int acc = 0;
        #pragma unroll
        for (int w = 0; w < 16; ++w) { woff[w] = acc; acc += wtot[w]; }
    }
    __syncthreads();
    int base = woff[wid] + v - s;
    #pragma unroll
    for (int k = 0; k < SCAN_PER / 4; ++k) {
        int i = lo + k * 4;
        if (i     <= NSUP) rp[i]     = base;  base += c[k].x;
        if (i + 1 <= NSUP) rp[i + 1] = base;  base += c[k].y;
        if (i + 2 <= NSUP) rp[i + 2] = base;  base += c[k].z;
        if (i + 3 <= NSUP) rp[i + 3] = base;  base += c[k].w;
    }
}

// ---------------- pixel scatter ----------------
__global__ __launch_bounds__(256) void pix_scatter(const int* __restrict__ seg,
        const int* __restrict__ rp, int* __restrict__ fill, int* __restrict__ pix) {
    int p = blockIdx.x * 256 + threadIdx.x;
    if (p >= NPIX) return;
    int s = seg[p];
    int pos = rp[s] + atomicAdd(fill + s, 1);
    pix[pos] = p;
}

// ---------------- edge scatter: u16 src + f32 weight ----------------
__global__ __launch_bounds__(256) void edge_scatter(const int* __restrict__ srcv,
        const int* __restrict__ dstv, const float* __restrict__ w,
        const int* __restrict__ rp, int* __restrict__ fill,
        unsigned short* __restrict__ src16, float* __restrict__ ew) {
    int e = blockIdx.x * 256 + threadIdx.x;
    if (e >= NE) return;
    int d = dstv[e];
    int pos = rp[d] + atomicAdd(fill + d, 1);
    src16[pos] = (unsigned short)srcv[e];   // NSUP = 50000 < 65536
    ew[pos] = w[e];
}

// ---------------- W transpose + bf16 convert: Wtb[l][n][k] = bf16(W[l][k][n]) ----------------
__global__ __launch_bounds__(256) void wconv(const float* __restrict__ W,
        unsigned short* __restrict__ Wtb) {
    int t = blockIdx.x * 256 + threadIdx.x;
    if (t >= NL * DD * DD) return;
    int l = t / (DD * DD);
    int rem = t - l * (DD * DD);
    int n = rem >> 7, k = rem & 127;
    Wtb[t] = f2bf(W[(size_t)l * DD * DD + (size_t)k * DD + n]);
}

// ---------------- pooling: half-wave per superpixel, 4-pixel unroll, bf16 out ----------------
__global__ __launch_bounds__(256) void pool_gather(const float* __restrict__ x,
        const int* __restrict__ pp, const int* __restrict__ pix, unsigned short* __restrict__ hb) {
    const int tid = threadIdx.x;
    const int wave = tid >> 6, lane = tid & 63;
    const int hf = lane >> 5, hl = lane & 31;
    const int row = blockIdx.x * 8 + wave * 2 + hf;
    const int j0 = pp[row], j1 = pp[row + 1];
    float4 a0 = make_float4(0.f, 0.f, 0.f, 0.f);
    float4 a1 = make_float4(0.f, 0.f, 0.f, 0.f);
    float4 a2 = make_float4(0.f, 0.f, 0.f, 0.f);
    float4 a3 = make_float4(0.f, 0.f, 0.f, 0.f);
    int j = j0;
    for (; j + 3 < j1; j += 4) {
        int p0 = pix[j], p1 = pix[j + 1], p2 = pix[j + 2], p3 = pix[j + 3];
        float4 v0 = *(const float4*)(x + rowoff(p0) + hl * 4);
        float4 v1 = *(const float4*)(x + rowoff(p1) + hl * 4);
        float4 v2 = *(const float4*)(x + rowoff(p2) + hl * 4);
        float4 v3 = *(const float4*)(x + rowoff(p3) + hl * 4);
        a0.x += v0.x; a0.y += v0.y; a0.z += v0.z; a0.w += v0.w;
        a1.x += v1.x; a1.y += v1.y; a1.z += v1.z; a1.w += v1.w;
        a2.x += v2.x; a2.y += v2.y; a2.z += v2.z; a2.w += v2.w;
        a3.x += v3.x; a3.y += v3.y; a3.z += v3.z; a3.w += v3.w;
    }
    for (; j < j1; ++j) {
        int p0 = pix[j];
        float4 v0 = *(const float4*)(x + rowoff(p0) + hl * 4);
        a0.x += v0.x; a0.y += v0.y; a0.z += v0.z; a0.w += v0.w;
    }
    float inv = 1.0f / fmaxf((float)(j1 - j0), 1.0f);
    float o0 = (a0.x + a1.x + a2.x + a3.x) * inv;
    float o1 = (a0.y + a1.y + a2.y + a3.y) * inv;
    float o2 = (a0.z + a1.z + a2.z + a3.z) * inv;
    float o3 = (a0.w + a1.w + a2.w + a3.w) * inv;
    uint2 pk;
    pk.x = (unsigned int)f2bf(o0) | ((unsigned int)f2bf(o1) << 16);
    pk.y = (unsigned int)f2bf(o2) | ((unsigned int)f2bf(o3) << 16);
    *(uint2*)(hb + rowoff(row) + hl * 4) = pk;
}

// ---------------- MFMA GEMM + fused y0, BN sc/sh computed in-block ----------------
// z = act(xib) @ W + b -> zb (row-major bf16); y0 = bf16(act(xib) + z) -> ya.
// FUSE=1: act(v) = leaky(v*sc + sh) with sc/sh derived from raw stats in LDS.
template <int FUSE>
__global__ __launch_bounds__(128) void gemm_mfma(const unsigned short* __restrict__ xib,
        const float* __restrict__ stats, const float* __restrict__ gamma,
        const float* __restrict__ beta, const unsigned short* __restrict__ Wtb,
        const float* __restrict__ bias, unsigned short* __restrict__ zb,
        unsigned short* __restrict__ y0) {
    __shared__ unsigned short act_s[64 * DD];   // 16 KB
    __shared__ unsigned short z_s[64 * DD];     // 16 KB
    __shared__ alignas(16) float scs[128];
    __shared__ alignas(16) float shs[128];
    if (FUSE) {
        if (threadIdx.x < 128) {
            int c = threadIdx.x;
            float mean = stats[c] * (1.0f / NSUP);
            float var = stats[128 + c] * (1.0f / NSUP) - mean * mean;
            float scale = gamma[c] / sqrtf(var + BN_EPS_C);
            scs[c] = scale;
            shs[c] = beta[c] - mean * scale;
        }
        __syncthreads();
    }
    const int wv = threadIdx.x >> 6;
    const int l  = threadIdx.x & 63;
    const int lr = l & 15;
    const int lk = (l >> 4) * 8;
    const int rbase = blockIdx.x * 64 + wv * 32;
    const int lbase = wv * 32;

    f32x4 acc[2][8];
    #pragma unroll
    for (int rt = 0; rt < 2; ++rt)
        #pragma unroll
        for (int nt = 0; nt < 8; ++nt)
            acc[rt][nt] = (f32x4){0.f, 0.f, 0.f, 0.f};

    #pragma unroll
    for (int kt = 0; kt < 4; ++kt) {
        const int kk = kt * 32 + lk;
        short8v bfr[8];
        #pragma unroll
        for (int nt = 0; nt < 8; ++nt)
            bfr[nt] = *(const short8v*)(Wtb + (size_t)(nt * 16 + lr) * DD + kk);
        float4 scv0, scv1, shv0, shv1;
        if (FUSE) {
            scv0 = *(const float4*)(scs + kk);
            scv1 = *(const float4*)(scs + kk + 4);
            shv0 = *(const float4*)(shs + kk);
            shv1 = *(const float4*)(shs + kk + 4);
        }
        #pragma unroll
        for (int rt = 0; rt < 2; ++rt) {
            int r = rbase + rt * 16 + lr;
            if (r >= NSUP) r = NSUP - 1;
            short8v a;
            if (FUSE) {
                uint4 av = *(const uint4*)(xib + (size_t)r * DD + kk);
                float f0 = lrelu(fmaf(bf2f_lo(av.x), scv0.x, shv0.x));
                float f1 = lrelu(fmaf(bf2f_hi(av.x), scv0.y, shv0.y));
                float f2 = lrelu(fmaf(bf2f_lo(av.y), scv0.z, shv0.z));
                float f3 = lrelu(fmaf(bf2f_hi(av.y), scv0.w, shv0.w));
                float f4 = lrelu(fmaf(bf2f_lo(av.z), scv1.x, shv1.x));
                float f5 = lrelu(fmaf(bf2f_hi(av.z), scv1.y, shv1.y));
                float f6 = lrelu(fmaf(bf2f_lo(av.w), scv1.z, shv1.z));
                float f7 = lrelu(fmaf(bf2f_hi(av.w), scv1.w, shv1.w));
                a[0] = (short)f2bf(f0); a[1] = (short)f2bf(f1);
                a[2] = (short)f2bf(f2); a[3] = (short)f2bf(f3);
                a[4] = (short)f2bf(f4); a[5] = (short)f2bf(f5);
                a[6] = (short)f2bf(f6); a[7] = (short)f2bf(f7);
            } else {
                a = *(const short8v*)(xib + (size_t)r * DD + kk);
            }
            *(short8v*)(act_s + (lbase + rt * 16 + lr) * DD + kk) = a;
            #pragma unroll
            for (int nt = 0; nt < 8; ++nt)
                acc[rt][nt] = __builtin_amdgcn_mfma_f32_16x16x32_bf16(a, bfr[nt], acc[rt][nt], 0, 0, 0);
        }
    }
    // epilogue: D layout col = l&15, row = (l>>4)*4 + j  [m89-verified]
    #pragma unroll
    for (int rt = 0; rt < 2; ++rt) {
        const int orow = rbase + rt * 16 + (l >> 4) * 4;
        const int lrow = lbase + rt * 16 + (l >> 4) * 4;
        #pragma unroll
        for (int nt = 0; nt < 8; ++nt) {
            const int col = nt * 16 + lr;
            const float bs = bias[col];
            #pragma unroll
            for (int j = 0; j < 4; ++j) {
                unsigned short zv = f2bf(acc[rt][nt][j] + bs);
                z_s[(lrow + j) * DD + col] = zv;
                int r = orow + j;
                if (r < NSUP)
                    zb[(size_t)r * DD + col] = zv;
            }
        }
    }
    __syncthreads();
    // phase 2: y0 = act + z, coalesced
    for (int i = threadIdx.x; i < 64 * 16; i += 128) {
        int lrow = i >> 4, g = i & 15;
        int r = blockIdx.x * 64 + lrow;
        if (r >= NSUP) continue;
        uint4 av = *(const uint4*)(act_s + lrow * DD + g * 8);
        uint4 zv = *(const uint4*)(z_s + lrow * DD + g * 8);
        float f0 = bf2f_lo(av.x) + bf2f_lo(zv.x), f1 = bf2f_hi(av.x) + bf2f_hi(zv.x);
        float f2 = bf2f_lo(av.y) + bf2f_lo(zv.y), f3 = bf2f_hi(av.y) + bf2f_hi(zv.y);
        float f4 = bf2f_lo(av.z) + bf2f_lo(zv.z), f5 = bf2f_hi(av.z) + bf2f_hi(zv.z);
        float f6 = bf2f_lo(av.w) + bf2f_lo(zv.w), f7 = bf2f_hi(av.w) + bf2f_hi(zv.w);
        uint4 o;
        o.x = (unsigned int)f2bf(f0) | ((unsigned int)f2bf(f1) << 16);
        o.y = (unsigned int)f2bf(f2) | ((unsigned int)f2bf(f3) << 16);
        o.z = (unsigned int)f2bf(f4) | ((unsigned int)f2bf(f5) << 16);
        o.w = (unsigned int)f2bf(f6) | ((unsigned int)f2bf(f7) << 16);
        *(uint4*)(y0 + (size_t)r * DD + g * 8) = o;
    }
}

// ---------------- SpMM: 256B rows, quarter-wave per row, u16 srcs, fused BN stats ----
// FINAL=0: yout = bf16( (A@y)*INV_C + zb )
// FINAL=1: xibout = bf16( (A@y)*INV_C ); block-reduced sum/sumsq -> stats_out
template <int FINAL>
__global__ __launch_bounds__(256) void spmm_q(const unsigned short* __restrict__ yin,
        const int* __restrict__ rp, const unsigned short* __restrict__ src16,
        const float* __restrict__ ew, const unsigned short* __restrict__ zb,
        unsigned short* __restrict__ xibout, unsigned short* __restrict__ yout,
        float* __restrict__ stats_out) {
    const int tid = threadIdx.x;
    const int wave = tid >> 6, lane = tid & 63;
    const int q = lane >> 4, ql = lane & 15;
    const int row = blockIdx.x * 16 + wave * 4 + q;
    const int j0 = rp[row], j1 = rp[row + 1];
    const size_t fo = (size_t)ql * 8;           // 8 bf16 = 16B per lane
    float a0 = 0.f, a1 = 0.f, a2 = 0.f, a3 = 0.f;
    float a4 = 0.f, a5 = 0.f, a6 = 0.f, a7 = 0.f;
    float b0 = 0.f, b1 = 0.f, b2 = 0.f, b3 = 0.f;
    float b4 = 0.f, b5 = 0.f, b6 = 0.f, b7 = 0.f;
    int j = j0;
    #define EDGE_FMA(ACC0,ACC1,ACC2,ACC3,ACC4,ACC5,ACC6,ACC7,U,W) \
        ACC0 = fmaf(W, bf2f_lo(U.x), ACC0); ACC1 = fmaf(W, bf2f_hi(U.x), ACC1); \
        ACC2 = fmaf(W, bf2f_lo(U.y), ACC2); ACC3 = fmaf(W, bf2f_hi(U.y), ACC3); \
        ACC4 = fmaf(W, bf2f_lo(U.z), ACC4); ACC5 = fmaf(W, bf2f_hi(U.z), ACC5); \
        ACC6 = fmaf(W, bf2f_lo(U.w), ACC6); ACC7 = fmaf(W, bf2f_hi(U.w), ACC7);
    for (; j + 8 <= j1; j += 8) {
        uint2 sa = *(const uint2*)(src16 + j);          // 4 u16 srcs
        uint2 sb = *(const uint2*)(src16 + j + 4);
        float4 wa = *(const float4*)(ew + j);
        float4 wb = *(const float4*)(ew + j + 4);
        uint4 u0 = *(const uint4*)(yin + rowoff(sa.x & 0xFFFF) + fo);
        uint4 u1 = *(const uint4*)(yin + rowoff(sa.x >> 16) + fo);
        uint4 u2 = *(const uint4*)(yin + rowoff(sa.y & 0xFFFF) + fo);
        uint4 u3 = *(const uint4*)(yin + rowoff(sa.y >> 16) + fo);
        uint4 u4 = *(const uint4*)(yin + rowoff(sb.x & 0xFFFF) + fo);
        uint4 u5 = *(const uint4*)(yin + rowoff(sb.x >> 16) + fo);
        uint4 u6 = *(const uint4*)(yin + rowoff(sb.y & 0xFFFF) + fo);
        uint4 u7 = *(const uint4*)(yin + rowoff(sb.y >> 16) + fo);
        EDGE_FMA(a0,a1,a2,a3,a4,a5,a6,a7, u0, wa.x)
        EDGE_FMA(b0,b1,b2,b3,b4,b5,b6,b7, u1, wa.y)
        EDGE_FMA(a0,a1,a2,a3,a4,a5,a6,a7, u2, wa.z)
        EDGE_FMA(b0,b1,b2,b3,b4,b5,b6,b7, u3, wa.w)
        EDGE_FMA(a0,a1,a2,a3,a4,a5,a6,a7, u4, wb.x)
        EDGE_FMA(b0,b1,b2,b3,b4,b5,b6,b7, u5, wb.y)
        EDGE_FMA(a0,a1,a2,a3,a4,a5,a6,a7, u6, wb.z)
        EDGE_FMA(b0,b1,b2,b3,b4,b5,b6,b7, u7, wb.w)
    }
    for (; j < j1; j += 4) {
        uint2 sa = *(const uint2*)(src16 + j);
        float4 wa = *(const float4*)(ew + j);
        uint4 u0 = *(const uint4*)(yin + rowoff(sa.x & 0xFFFF) + fo);
        uint4 u1 = *(const uint4*)(yin + rowoff(sa.x >> 16) + fo);
        uint4 u2 = *(const uint4*)(yin + rowoff(sa.y & 0xFFFF) + fo);
        uint4 u3 = *(const uint4*)(yin + rowoff(sa.y >> 16) + fo);
        EDGE_FMA(a0,a1,a2,a3,a4,a5,a6,a7, u0, wa.x)
        EDGE_FMA(b0,b1,b2,b3,b4,b5,b6,b7, u1, wa.y)
        EDGE_FMA(a0,a1,a2,a3,a4,a5,a6,a7, u2, wa.z)
        EDGE_FMA(b0,b1,b2,b3,b4,b5,b6,b7, u3, wa.w)
    }
    #undef EDGE_FMA
    float s0 = (a0 + b0) * INV_C, s1 = (a1 + b1) * INV_C;
    float s2 = (a2 + b2) * INV_C, s3 = (a3 + b3) * INV_C;
    float s4 = (a4 + b4) * INV_C, s5 = (a5 + b5) * INV_C;
    float s6 = (a6 + b6) * INV_C, s7 = (a7 + b7) * INV_C;
    if constexpr (FINAL) {
        uint4 o;
        o.x = (unsigned int)f2bf(s0) | ((unsigned int)f2bf(s1) << 16);
        o.y = (unsigned int)f2bf(s2) | ((unsigned int)f2bf(s3) << 16);
        o.z = (unsigned int)f2bf(s4) | ((unsigned int)f2bf(s5) << 16);
        o.w = (unsigned int)f2bf(s6) | ((unsigned int)f2bf(s7) << 16);
        *(uint4*)(xibout + rowoff(row) + fo) = o;
        // fused BN stats: sum / sumsq per channel (channels = ql*8 .. ql*8+7)
        __shared__ float ls[256][8];
        __shared__ float lq[256][8];
        float v[8] = {s0, s1, s2, s3, s4, s5, s6, s7};
        #pragma unroll
        for (int k = 0; k < 8; ++k) { ls[tid][k] = v[k]; lq[tid][k] = v[k] * v[k]; }
        __syncthreads();
        for (int off = 128; off >= 16; off >>= 1) {
            if (tid < off) {
                #pragma unroll
                for (int k = 0; k < 8; ++k) {
                    ls[tid][k] += ls[tid + off][k];
                    lq[tid][k] += lq[tid + off][k];
                }
            }
            __syncthreads();
        }
        if (tid < 16) {     // tid == ql after reduction (offsets are multiples of 16)
            #pragma unroll
            for (int k = 0; k < 8; ++k) {
                atomicAdd(&stats_out[tid * 8 + k], ls[tid][k]);
                atomicAdd(&stats_out[128 + tid * 8 + k], lq[tid][k]);
            }
        }
    } else {
        uint4 zv = *(const uint4*)(zb + rowoff(row) + fo);
        s0 += bf2f_lo(zv.x); s1 += bf2f_hi(zv.x);
        s2 += bf2f_lo(zv.y); s3 += bf2f_hi(zv.y);
        s4 += bf2f_lo(zv.z); s5 += bf2f_hi(zv.z);
        s6 += bf2f_lo(zv.w); s7 += bf2f_hi(zv.w);
        uint4 o;
        o.x = (unsigned int)f2bf(s0) | ((unsigned int)f2bf(s1) << 16);
        o.y = (unsigned int)f2bf(s2) | ((unsigned int)f2bf(s3) << 16);
        o.z = (unsigned int)f2bf(s4) | ((unsigned int)f2bf(s5) << 16);
        o.w = (unsigned int)f2bf(s6) | ((unsigned int)f2bf(s7) << 16);
        *(uint4*)(yout + rowoff(row) + fo) = o;
    }
}

// ---------------- unpool with fused final BN+leaky (sc/sh from raw stats) ----------------
__global__ __launch_bounds__(256) void unpool_bn(const unsigned short* __restrict__ xib,
        const float* __restrict__ stats, const float* __restrict__ gamma,
        const float* __restrict__ beta, const int* __restrict__ seg,
        float* __restrict__ out) {
    __shared__ alignas(16) float scs[128];
    __shared__ alignas(16) float shs[128];
    if (threadIdx.x < 128) {
        int c = threadIdx.x;
        float mean = stats[c] * (1.0f / NSUP);
        float var = stats[128 + c] * (1.0f / NSUP) - mean * mean;
        float scale = gamma[c] / sqrtf(var + BN_EPS_C);
        scs[c] = scale;
        shs[c] = beta[c] - mean * scale;
    }
    __syncthreads();
    int t = blockIdx.x * 256 + threadIdx.x;     // NPIX*16
    int p = t >> 4, g = t & 15;
    int s = seg[p];
    int col = g * 8;
    uint4 v = *(const uint4*)(xib + (size_t)s * DD + col);
    float4 sc0 = *(const float4*)(scs + col), sc1 = *(const float4*)(scs + col + 4);
    float4 sh0 = *(const float4*)(shs + col), sh1 = *(const float4*)(shs + col + 4);
    float4 o0, o1;
    o0.x = lrelu(fmaf(bf2f_lo(v.x), sc0.x, sh0.x));
    o0.y = lrelu(fmaf(bf2f_hi(v.x), sc0.y, sh0.y));
    o0.z = lrelu(fmaf(bf2f_lo(v.y), sc0.z, sh0.z));
    o0.w = lrelu(fmaf(bf2f_hi(v.y), sc0.w, sh0.w));
    o1.x = lrelu(fmaf(bf2f_lo(v.z), sc1.x, sh1.x));
    o1.y = lrelu(fmaf(bf2f_hi(v.z), sc1.y, sh1.y));
    o1.z = lrelu(fmaf(bf2f_lo(v.w), sc1.z, sh1.z));
    o1.w = lrelu(fmaf(bf2f_hi(v.w), sc1.w, sh1.w));
    *(float4*)(out + (size_t)p * DD + col) = o0;
    *(float4*)(out + (size_t)p * DD + col + 4) = o1;
}

extern "C" void kernel_launch(void* const* d_in, const int* in_sizes, int n_in,
                              void* d_out, int out_size, void* d_ws, size_t ws_size,
                              hipStream_t stream) {
    const float* x     = (const float*)d_in[0];
    const float* W     = (const float*)d_in[1];
    const float* b     = (const float*)d_in[2];
    const float* gamma = (const float*)d_in[3];
    const float* beta  = (const float*)d_in[4];
    const float* ewt   = (const float*)d_in[5];
    const int*   seg   = (const int*)d_in[6];
    const int*   eidx  = (const int*)d_in[7];
    const int*   esrc  = eidx;
    const int*   edst  = eidx + NE;
    float* out = (float*)d_out;

    // d_out hosts transients zb | ya | yb (bf16 row-major, 38.4MB), dead before unpool.
    const size_t MAT = (size_t)NSUP * DD;
    unsigned short* zb = (unsigned short*)out;
    unsigned short* ya = zb + MAT;
    unsigned short* yb = ya + MAT;

    char* ws = (char*)d_ws;
    size_t off = 0;
    auto alloc = [&](size_t bytes) -> void* {
        void* p = ws + off;
        off = (off + bytes + 255) & ~(size_t)255;
        return p;
    };
    unsigned short* xib = (unsigned short*)alloc(sizeof(unsigned short) * MAT);  // 12.8 MB
    unsigned short* hb  = (unsigned short*)alloc(sizeof(unsigned short) * MAT);  // 12.8 MB
    unsigned short* Wtb = (unsigned short*)alloc(sizeof(unsigned short) * NL * DD * DD);
    int*   rowcnt  = (int*)alloc(sizeof(int) * CNT_CAP);
    int*   rowptr  = (int*)alloc(sizeof(int) * (NSUP + 1));
    int*   rowfill = (int*)alloc(sizeof(int) * NSUP);
    int*   pixcnt  = (int*)alloc(sizeof(int) * CNT_CAP);
    int*   pixptr  = (int*)alloc(sizeof(int) * (NSUP + 1));
    int*   pixfill = (int*)alloc(sizeof(int) * NSUP);
    int*   pixids  = (int*)alloc(sizeof(int) * NPIX);
    unsigned short* src16 = (unsigned short*)alloc(sizeof(unsigned short) * NEPAD4);
    float* ew      = (float*)alloc(sizeof(float) * NEPAD4);
    float* statsbf = (float*)alloc(sizeof(float) * NL * 256);    // per-layer sums

    hipMemsetAsync(rowcnt, 0, sizeof(int) * CNT_CAP, stream);
    hipMemsetAsync(rowfill, 0, sizeof(int) * NSUP, stream);
    hipMemsetAsync(pixcnt, 0, sizeof(int) * CNT_CAP, stream);
    hipMemsetAsync(pixfill, 0, sizeof(int) * NSUP, stream);
    hipMemsetAsync(src16, 0, sizeof(unsigned short) * NEPAD4, stream);  // pad -> src 0
    hipMemsetAsync(ew, 0, sizeof(float) * NEPAD4, stream);              // pad -> w 0.0
    hipMemsetAsync(statsbf, 0, sizeof(float) * NL * 256, stream);

    // W transpose+bf16 (all layers)
    wconv<<<(NL * DD * DD + 255) / 256, 256, 0, stream>>>(W, Wtb);

    // pixel CSR + pooling
    hist_k<<<(NPIX + 255) / 256, 256, 0, stream>>>(seg, pixcnt, NPIX);
    scan_rowptr<1><<<1, 1024, 0, stream>>>(pixcnt, pixptr);
    pix_scatter<<<(NPIX + 255) / 256, 256, 0, stream>>>(seg, pixptr, pixfill, pixids);
    pool_gather<<<NSUP / 8, 256, 0, stream>>>(x, pixptr, pixids, hb);

    // edge CSR by dst, rows padded to multiple of 4 (u16 src + f32 w)
    hist_k<<<(NE + 255) / 256, 256, 0, stream>>>(edst, rowcnt, NE);
    scan_rowptr<4><<<1, 1024, 0, stream>>>(rowcnt, rowptr);
    edge_scatter<<<(NE + 255) / 256, 256, 0, stream>>>(esrc, edst, ewt, rowptr, rowfill,
                                                       src16, ew);

    // 5 SFNet layers
    const int ggrid = (NSUP + 63) / 64;
    for (int i = 0; i < NL; ++i) {
        if (i == 0)
            gemm_mfma<0><<<ggrid, 128, 0, stream>>>(hb, nullptr, nullptr, nullptr,
                    Wtb + (size_t)i * DD * DD, b + i * DD, zb, ya);
        else
            gemm_mfma<1><<<ggrid, 128, 0, stream>>>(xib, statsbf + (i - 1) * 256,
                    gamma + (size_t)(i - 1) * DD, beta + (size_t)(i - 1) * DD,
                    Wtb + (size_t)i * DD * DD, b + i * DD, zb, ya);

        const unsigned short* ycur = ya;
        unsigned short* ynxt = yb;
        for (int t = 0; t < 4; ++t) {
            spmm_q<0><<<NSUP / 16, 256, 0, stream>>>(ycur, rowptr, src16, ew, zb,
                                                     nullptr, ynxt, nullptr);
            const unsigned short* tmp = ycur;
            ycur = ynxt;
            ynxt = (unsigned short*)tmp;
        }
        spmm_q<1><<<NSUP / 16, 256, 0, stream>>>(ycur, rowptr, src16, ew, nullptr,
                                                 xib, nullptr, statsbf + i * 256);
    }

    // final: BN+leaky fused into unpool (overwrites all of d_out)
    unpool_bn<<<NPIX * 16 / 256, 256, 0, stream>>>(xib, statsbf + (NL - 1) * 256,
            gamma + (size_t)(NL - 1) * DD, beta + (size_t)(NL - 1) * DD, seg, out);
}

// Round 10
// 1265.398 us; speedup vs baseline: 3.1866x; 3.1866x over previous
//
#include <hip/hip_runtime.h>

#define NPIX 250000
#define NSUP 50000
#define NE   800000
#define DD   128
#define NL   5

#define BN_EPS_C 1e-5f
#define SLOPE 0.01f
#define INV_C (1.0f / 2.9f)

// edge capacity with per-row pad to multiple of 4
#define NEPAD4 (NE + 3 * NSUP)
#define SCAN_PER 52
#define CNT_CAP (1024 * SCAN_PER)

typedef __attribute__((ext_vector_type(8))) short short8v;   // 8 bf16 (4 VGPR)
typedef __attribute__((ext_vector_type(4))) float f32x4;     // MFMA acc

__device__ __forceinline__ size_t rowoff(int r) { return (size_t)r * DD; }

__device__ __forceinline__ unsigned short f2bf(float f) {
    unsigned int u = __float_as_uint(f);
    unsigned int r = (u + 0x7FFFu + ((u >> 16) & 1u)) >> 16;
    return (unsigned short)r;
}
__device__ __forceinline__ float bf2f_lo(unsigned int v) { return __uint_as_float(v << 16); }
__device__ __forceinline__ float bf2f_hi(unsigned int v) { return __uint_as_float(v & 0xFFFF0000u); }
__device__ __forceinline__ float lrelu(float o) { return o > 0.f ? o : SLOPE * o; }

// ---------------- generic histogram ----------------
__global__ __launch_bounds__(256) void hist_k(const int* __restrict__ ids,
        int* __restrict__ cnt, int n) {
    int e = blockIdx.x * 256 + threadIdx.x;
    if (e >= n) return;
    atomicAdd(cnt + ids[e], 1);
}

// ---------------- single-block scan over padded counters ----------------
template <int PAD>
__global__ __launch_bounds__(1024) void scan_rowptr(const int* __restrict__ cnt,
        int* __restrict__ rp) {
    const int t = threadIdx.x;
    const int lo = t * SCAN_PER;
    int4 c[SCAN_PER / 4];
    int s = 0;
    #pragma unroll
    for (int k = 0; k < SCAN_PER / 4; ++k) {
        int4 v = *(const int4*)(cnt + lo + k * 4);
        if (PAD > 1) {
            v.x = (v.x + PAD - 1) & ~(PAD - 1);
            v.y = (v.y + PAD - 1) & ~(PAD - 1);
            v.z = (v.z + PAD - 1) & ~(PAD - 1);
            v.w = (v.w + PAD - 1) & ~(PAD - 1);
        }
        c[k] = v;
        s += v.x + v.y + v.z + v.w;
    }
    int lane = t & 63, wid = t >> 6;
    int v = s;
    #pragma unroll
    for (int d = 1; d < 64; d <<= 1) {
        int u = __shfl_up(v, d);
        if (lane >= d) v += u;
    }
    __shared__ int wtot[16], woff[16];
    if (lane == 63) wtot[wid] = v;
    __syncthreads();
    if (t == 0) {
        int acc = 0;
        #pragma unroll
        for (int w = 0; w < 16; ++w) { woff[w] = acc; acc += wtot[w]; }
    }
    __syncthreads();
    int base = woff[wid] + v - s;
    #pragma unroll
    for (int k = 0; k < SCAN_PER / 4; ++k) {
        int i = lo + k * 4;
        if (i     <= NSUP) rp[i]     = base;  base += c[k].x;
        if (i + 1 <= NSUP) rp[i + 1] = base;  base += c[k].y;
        if (i + 2 <= NSUP) rp[i + 2] = base;  base += c[k].z;
        if (i + 3 <= NSUP) rp[i + 3] = base;  base += c[k].w;
    }
}

// ---------------- pixel scatter ----------------
__global__ __launch_bounds__(256) void pix_scatter(const int* __restrict__ seg,
        const int* __restrict__ rp, int* __restrict__ fill, int* __restrict__ pix) {
    int p = blockIdx.x * 256 + threadIdx.x;
    if (p >= NPIX) return;
    int s = seg[p];
    int pos = rp[s] + atomicAdd(fill + s, 1);
    pix[pos] = p;
}

// ---------------- edge scatter: u16 src + f32 weight ----------------
__global__ __launch_bounds__(256) void edge_scatter(const int* __restrict__ srcv,
        const int* __restrict__ dstv, const float* __restrict__ w,
        const int* __restrict__ rp, int* __restrict__ fill,
        unsigned short* __restrict__ src16, float* __restrict__ ew) {
    int e = blockIdx.x * 256 + threadIdx.x;
    if (e >= NE) return;
    int d = dstv[e];
    int pos = rp[d] + atomicAdd(fill + d, 1);
    src16[pos] = (unsigned short)srcv[e];   // NSUP = 50000 < 65536
    ew[pos] = w[e];
}

// ---------------- W transpose + bf16 convert: Wtb[l][n][k] = bf16(W[l][k][n]) ----------------
__global__ __launch_bounds__(256) void wconv(const float* __restrict__ W,
        unsigned short* __restrict__ Wtb) {
    int t = blockIdx.x * 256 + threadIdx.x;
    if (t >= NL * DD * DD) return;
    int l = t / (DD * DD);
    int rem = t - l * (DD * DD);
    int n = rem >> 7, k = rem & 127;
    Wtb[t] = f2bf(W[(size_t)l * DD * DD + (size_t)k * DD + n]);
}

// ---------------- pooling: half-wave per superpixel, 4-pixel unroll, bf16 out ----------------
__global__ __launch_bounds__(256) void pool_gather(const float* __restrict__ x,
        const int* __restrict__ pp, const int* __restrict__ pix, unsigned short* __restrict__ hb) {
    const int tid = threadIdx.x;
    const int wave = tid >> 6, lane = tid & 63;
    const int hf = lane >> 5, hl = lane & 31;
    const int row = blockIdx.x * 8 + wave * 2 + hf;
    const int j0 = pp[row], j1 = pp[row + 1];
    float4 a0 = make_float4(0.f, 0.f, 0.f, 0.f);
    float4 a1 = make_float4(0.f, 0.f, 0.f, 0.f);
    float4 a2 = make_float4(0.f, 0.f, 0.f, 0.f);
    float4 a3 = make_float4(0.f, 0.f, 0.f, 0.f);
    int j = j0;
    for (; j + 3 < j1; j += 4) {
        int p0 = pix[j], p1 = pix[j + 1], p2 = pix[j + 2], p3 = pix[j + 3];
        float4 v0 = *(const float4*)(x + rowoff(p0) + hl * 4);
        float4 v1 = *(const float4*)(x + rowoff(p1) + hl * 4);
        float4 v2 = *(const float4*)(x + rowoff(p2) + hl * 4);
        float4 v3 = *(const float4*)(x + rowoff(p3) + hl * 4);
        a0.x += v0.x; a0.y += v0.y; a0.z += v0.z; a0.w += v0.w;
        a1.x += v1.x; a1.y += v1.y; a1.z += v1.z; a1.w += v1.w;
        a2.x += v2.x; a2.y += v2.y; a2.z += v2.z; a2.w += v2.w;
        a3.x += v3.x; a3.y += v3.y; a3.z += v3.z; a3.w += v3.w;
    }
    for (; j < j1; ++j) {
        int p0 = pix[j];
        float4 v0 = *(const float4*)(x + rowoff(p0) + hl * 4);
        a0.x += v0.x; a0.y += v0.y; a0.z += v0.z; a0.w += v0.w;
    }
    float inv = 1.0f / fmaxf((float)(j1 - j0), 1.0f);
    float o0 = (a0.x + a1.x + a2.x + a3.x) * inv;
    float o1 = (a0.y + a1.y + a2.y + a3.y) * inv;
    float o2 = (a0.z + a1.z + a2.z + a3.z) * inv;
    float o3 = (a0.w + a1.w + a2.w + a3.w) * inv;
    uint2 pk;
    pk.x = (unsigned int)f2bf(o0) | ((unsigned int)f2bf(o1) << 16);
    pk.y = (unsigned int)f2bf(o2) | ((unsigned int)f2bf(o3) << 16);
    *(uint2*)(hb + rowoff(row) + hl * 4) = pk;
}

// ---------------- MFMA GEMM + fused y0, BN sc/sh computed in-block ----------------
// z = act(xib) @ W + b -> zb (row-major bf16); y0 = bf16(act(xib) + z) -> ya.
// FUSE=1: act(v) = leaky(v*sc + sh) with sc/sh derived from raw stats in LDS.
template <int FUSE>
__global__ __launch_bounds__(128) void gemm_mfma(const unsigned short* __restrict__ xib,
        const float* __restrict__ stats, const float* __restrict__ gamma,
        const float* __restrict__ beta, const unsigned short* __restrict__ Wtb,
        const float* __restrict__ bias, unsigned short* __restrict__ zb,
        unsigned short* __restrict__ y0) {
    __shared__ unsigned short act_s[64 * DD];   // 16 KB
    __shared__ unsigned short z_s[64 * DD];     // 16 KB
    __shared__ alignas(16) float scs[128];
    __shared__ alignas(16) float shs[128];
    if (FUSE) {
        if (threadIdx.x < 128) {
            int c = threadIdx.x;
            float mean = stats[c] * (1.0f / NSUP);
            float var = stats[128 + c] * (1.0f / NSUP) - mean * mean;
            float scale = gamma[c] / sqrtf(var + BN_EPS_C);
            scs[c] = scale;
            shs[c] = beta[c] - mean * scale;
        }
        __syncthreads();
    }
    const int wv = threadIdx.x >> 6;
    const int l  = threadIdx.x & 63;
    const int lr = l & 15;
    const int lk = (l >> 4) * 8;
    const int rbase = blockIdx.x * 64 + wv * 32;
    const int lbase = wv * 32;

    f32x4 acc[2][8];
    #pragma unroll
    for (int rt = 0; rt < 2; ++rt)
        #pragma unroll
        for (int nt = 0; nt < 8; ++nt)
            acc[rt][nt] = (f32x4){0.f, 0.f, 0.f, 0.f};

    #pragma unroll
    for (int kt = 0; kt < 4; ++kt) {
        const int kk = kt * 32 + lk;
        short8v bfr[8];
        #pragma unroll
        for (int nt = 0; nt < 8; ++nt)
            bfr[nt] = *(const short8v*)(Wtb + (size_t)(nt * 16 + lr) * DD + kk);
        float4 scv0, scv1, shv0, shv1;
        if (FUSE) {
            scv0 = *(const float4*)(scs + kk);
            scv1 = *(const float4*)(scs + kk + 4);
            shv0 = *(const float4*)(shs + kk);
            shv1 = *(const float4*)(shs + kk + 4);
        }
        #pragma unroll
        for (int rt = 0; rt < 2; ++rt) {
            int r = rbase + rt * 16 + lr;
            if (r >= NSUP) r = NSUP - 1;
            short8v a;
            if (FUSE) {
                uint4 av = *(const uint4*)(xib + (size_t)r * DD + kk);
                float f0 = lrelu(fmaf(bf2f_lo(av.x), scv0.x, shv0.x));
                float f1 = lrelu(fmaf(bf2f_hi(av.x), scv0.y, shv0.y));
                float f2 = lrelu(fmaf(bf2f_lo(av.y), scv0.z, shv0.z));
                float f3 = lrelu(fmaf(bf2f_hi(av.y), scv0.w, shv0.w));
                float f4 = lrelu(fmaf(bf2f_lo(av.z), scv1.x, shv1.x));
                float f5 = lrelu(fmaf(bf2f_hi(av.z), scv1.y, shv1.y));
                float f6 = lrelu(fmaf(bf2f_lo(av.w), scv1.z, shv1.z));
                float f7 = lrelu(fmaf(bf2f_hi(av.w), scv1.w, shv1.w));
                a[0] = (short)f2bf(f0); a[1] = (short)f2bf(f1);
                a[2] = (short)f2bf(f2); a[3] = (short)f2bf(f3);
                a[4] = (short)f2bf(f4); a[5] = (short)f2bf(f5);
                a[6] = (short)f2bf(f6); a[7] = (short)f2bf(f7);
            } else {
                a = *(const short8v*)(xib + (size_t)r * DD + kk);
            }
            *(short8v*)(act_s + (lbase + rt * 16 + lr) * DD + kk) = a;
            #pragma unroll
            for (int nt = 0; nt < 8; ++nt)
                acc[rt][nt] = __builtin_amdgcn_mfma_f32_16x16x32_bf16(a, bfr[nt], acc[rt][nt], 0, 0, 0);
        }
    }
    // epilogue: D layout col = l&15, row = (l>>4)*4 + j  [m89-verified]
    #pragma unroll
    for (int rt = 0; rt < 2; ++rt) {
        const int orow = rbase + rt * 16 + (l >> 4) * 4;
        const int lrow = lbase + rt * 16 + (l >> 4) * 4;
        #pragma unroll
        for (int nt = 0; nt < 8; ++nt) {
            const int col = nt * 16 + lr;
            const float bs = bias[col];
            #pragma unroll
            for (int j = 0; j < 4; ++j) {
                unsigned short zv = f2bf(acc[rt][nt][j] + bs);
                z_s[(lrow + j) * DD + col] = zv;
                int r = orow + j;
                if (r < NSUP)
                    zb[(size_t)r * DD + col] = zv;
            }
        }
    }
    __syncthreads();
    // phase 2: y0 = act + z, coalesced
    for (int i = threadIdx.x; i < 64 * 16; i += 128) {
        int lrow = i >> 4, g = i & 15;
        int r = blockIdx.x * 64 + lrow;
        if (r >= NSUP) continue;
        uint4 av = *(const uint4*)(act_s + lrow * DD + g * 8);
        uint4 zv = *(const uint4*)(z_s + lrow * DD + g * 8);
        float f0 = bf2f_lo(av.x) + bf2f_lo(zv.x), f1 = bf2f_hi(av.x) + bf2f_hi(zv.x);
        float f2 = bf2f_lo(av.y) + bf2f_lo(zv.y), f3 = bf2f_hi(av.y) + bf2f_hi(zv.y);
        float f4 = bf2f_lo(av.z) + bf2f_lo(zv.z), f5 = bf2f_hi(av.z) + bf2f_hi(zv.z);
        float f6 = bf2f_lo(av.w) + bf2f_lo(zv.w), f7 = bf2f_hi(av.w) + bf2f_hi(zv.w);
        uint4 o;
        o.x = (unsigned int)f2bf(f0) | ((unsigned int)f2bf(f1) << 16);
        o.y = (unsigned int)f2bf(f2) | ((unsigned int)f2bf(f3) << 16);
        o.z = (unsigned int)f2bf(f4) | ((unsigned int)f2bf(f5) << 16);
        o.w = (unsigned int)f2bf(f6) | ((unsigned int)f2bf(f7) << 16);
        *(uint4*)(y0 + (size_t)r * DD + g * 8) = o;
    }
}

// ---------------- SpMM: 256B rows, quarter-wave per row, u16 srcs, 8-deep ILP ----------
// FINAL=0: yout = bf16( (A@y)*INV_C + zb )
// FINAL=1: xibout = bf16( (A@y)*INV_C )
template <int FINAL>
__global__ __launch_bounds__(256) void spmm_q(const unsigned short* __restrict__ yin,
        const int* __restrict__ rp, const unsigned short* __restrict__ src16,
        const float* __restrict__ ew, const unsigned short* __restrict__ zb,
        unsigned short* __restrict__ xibout, unsigned short* __restrict__ yout) {
    const int tid = threadIdx.x;
    const int wave = tid >> 6, lane = tid & 63;
    const int q = lane >> 4, ql = lane & 15;
    const int row = blockIdx.x * 16 + wave * 4 + q;
    const int j0 = rp[row], j1 = rp[row + 1];
    const size_t fo = (size_t)ql * 8;           // 8 bf16 = 16B per lane
    float a0 = 0.f, a1 = 0.f, a2 = 0.f, a3 = 0.f;
    float a4 = 0.f, a5 = 0.f, a6 = 0.f, a7 = 0.f;
    float b0 = 0.f, b1 = 0.f, b2 = 0.f, b3 = 0.f;
    float b4 = 0.f, b5 = 0.f, b6 = 0.f, b7 = 0.f;
    int j = j0;
    #define EDGE_FMA(ACC0,ACC1,ACC2,ACC3,ACC4,ACC5,ACC6,ACC7,U,W) \
        ACC0 = fmaf(W, bf2f_lo(U.x), ACC0); ACC1 = fmaf(W, bf2f_hi(U.x), ACC1); \
        ACC2 = fmaf(W, bf2f_lo(U.y), ACC2); ACC3 = fmaf(W, bf2f_hi(U.y), ACC3); \
        ACC4 = fmaf(W, bf2f_lo(U.z), ACC4); ACC5 = fmaf(W, bf2f_hi(U.z), ACC5); \
        ACC6 = fmaf(W, bf2f_lo(U.w), ACC6); ACC7 = fmaf(W, bf2f_hi(U.w), ACC7);
    for (; j + 8 <= j1; j += 8) {
        uint2 sa = *(const uint2*)(src16 + j);          // 4 u16 srcs
        uint2 sb = *(const uint2*)(src16 + j + 4);
        float4 wa = *(const float4*)(ew + j);
        float4 wb = *(const float4*)(ew + j + 4);
        uint4 u0 = *(const uint4*)(yin + rowoff(sa.x & 0xFFFF) + fo);
        uint4 u1 = *(const uint4*)(yin + rowoff(sa.x >> 16) + fo);
        uint4 u2 = *(const uint4*)(yin + rowoff(sa.y & 0xFFFF) + fo);
        uint4 u3 = *(const uint4*)(yin + rowoff(sa.y >> 16) + fo);
        uint4 u4 = *(const uint4*)(yin + rowoff(sb.x & 0xFFFF) + fo);
        uint4 u5 = *(const uint4*)(yin + rowoff(sb.x >> 16) + fo);
        uint4 u6 = *(const uint4*)(yin + rowoff(sb.y & 0xFFFF) + fo);
        uint4 u7 = *(const uint4*)(yin + rowoff(sb.y >> 16) + fo);
        EDGE_FMA(a0,a1,a2,a3,a4,a5,a6,a7, u0, wa.x)
        EDGE_FMA(b0,b1,b2,b3,b4,b5,b6,b7, u1, wa.y)
        EDGE_FMA(a0,a1,a2,a3,a4,a5,a6,a7, u2, wa.z)
        EDGE_FMA(b0,b1,b2,b3,b4,b5,b6,b7, u3, wa.w)
        EDGE_FMA(a0,a1,a2,a3,a4,a5,a6,a7, u4, wb.x)
        EDGE_FMA(b0,b1,b2,b3,b4,b5,b6,b7, u5, wb.y)
        EDGE_FMA(a0,a1,a2,a3,a4,a5,a6,a7, u6, wb.z)
        EDGE_FMA(b0,b1,b2,b3,b4,b5,b6,b7, u7, wb.w)
    }
    for (; j < j1; j += 4) {
        uint2 sa = *(const uint2*)(src16 + j);
        float4 wa = *(const float4*)(ew + j);
        uint4 u0 = *(const uint4*)(yin + rowoff(sa.x & 0xFFFF) + fo);
        uint4 u1 = *(const uint4*)(yin + rowoff(sa.x >> 16) + fo);
        uint4 u2 = *(const uint4*)(yin + rowoff(sa.y & 0xFFFF) + fo);
        uint4 u3 = *(const uint4*)(yin + rowoff(sa.y >> 16) + fo);
        EDGE_FMA(a0,a1,a2,a3,a4,a5,a6,a7, u0, wa.x)
        EDGE_FMA(b0,b1,b2,b3,b4,b5,b6,b7, u1, wa.y)
        EDGE_FMA(a0,a1,a2,a3,a4,a5,a6,a7, u2, wa.z)
        EDGE_FMA(b0,b1,b2,b3,b4,b5,b6,b7, u3, wa.w)
    }
    #undef EDGE_FMA
    float s0 = (a0 + b0) * INV_C, s1 = (a1 + b1) * INV_C;
    float s2 = (a2 + b2) * INV_C, s3 = (a3 + b3) * INV_C;
    float s4 = (a4 + b4) * INV_C, s5 = (a5 + b5) * INV_C;
    float s6 = (a6 + b6) * INV_C, s7 = (a7 + b7) * INV_C;
    if (!FINAL) {
        uint4 zv = *(const uint4*)(zb + rowoff(row) + fo);
        s0 += bf2f_lo(zv.x); s1 += bf2f_hi(zv.x);
        s2 += bf2f_lo(zv.y); s3 += bf2f_hi(zv.y);
        s4 += bf2f_lo(zv.z); s5 += bf2f_hi(zv.z);
        s6 += bf2f_lo(zv.w); s7 += bf2f_hi(zv.w);
    }
    uint4 o;
    o.x = (unsigned int)f2bf(s0) | ((unsigned int)f2bf(s1) << 16);
    o.y = (unsigned int)f2bf(s2) | ((unsigned int)f2bf(s3) << 16);
    o.z = (unsigned int)f2bf(s4) | ((unsigned int)f2bf(s5) << 16);
    o.w = (unsigned int)f2bf(s6) | ((unsigned int)f2bf(s7) << 16);
    if (FINAL)
        *(uint4*)(xibout + rowoff(row) + fo) = o;
    else
        *(uint4*)(yout + rowoff(row) + fo) = o;
}

// ---------------- BatchNorm stats over bf16 xi (standalone, 128 blocks) ----------------
__global__ __launch_bounds__(256) void bn_stats(const unsigned short* __restrict__ xib,
        float* __restrict__ sums) {
    const int cg = threadIdx.x & 15;
    const int rs = threadIdx.x >> 4;
    float s[8], q[8];
    #pragma unroll
    for (int k = 0; k < 8; ++k) { s[k] = 0.f; q[k] = 0.f; }
    for (int r = blockIdx.x * 16 + rs; r < NSUP; r += gridDim.x * 16) {
        uint4 v = *(const uint4*)(xib + (size_t)r * DD + cg * 8);
        float f0 = bf2f_lo(v.x), f1 = bf2f_hi(v.x), f2 = bf2f_lo(v.y), f3 = bf2f_hi(v.y);
        float f4 = bf2f_lo(v.z), f5 = bf2f_hi(v.z), f6 = bf2f_lo(v.w), f7 = bf2f_hi(v.w);
        s[0] += f0; q[0] = fmaf(f0, f0, q[0]);
        s[1] += f1; q[1] = fmaf(f1, f1, q[1]);
        s[2] += f2; q[2] = fmaf(f2, f2, q[2]);
        s[3] += f3; q[3] = fmaf(f3, f3, q[3]);
        s[4] += f4; q[4] = fmaf(f4, f4, q[4]);
        s[5] += f5; q[5] = fmaf(f5, f5, q[5]);
        s[6] += f6; q[6] = fmaf(f6, f6, q[6]);
        s[7] += f7; q[7] = fmaf(f7, f7, q[7]);
    }
    __shared__ float ls[256][8];
    __shared__ float lq[256][8];
    #pragma unroll
    for (int k = 0; k < 8; ++k) { ls[threadIdx.x][k] = s[k]; lq[threadIdx.x][k] = q[k]; }
    __syncthreads();
    for (int off = 128; off >= 16; off >>= 1) {
        if (threadIdx.x < off) {
            #pragma unroll
            for (int k = 0; k < 8; ++k) {
                ls[threadIdx.x][k] += ls[threadIdx.x + off][k];
                lq[threadIdx.x][k] += lq[threadIdx.x + off][k];
            }
        }
        __syncthreads();
    }
    if (threadIdx.x < 16) {
        #pragma unroll
        for (int k = 0; k < 8; ++k) {
            atomicAdd(&sums[threadIdx.x * 8 + k], ls[threadIdx.x][k]);
            atomicAdd(&sums[128 + threadIdx.x * 8 + k], lq[threadIdx.x][k]);
        }
    }
}

// ---------------- unpool with fused final BN+leaky (sc/sh from raw stats) ----------------
__global__ __launch_bounds__(256) void unpool_bn(const unsigned short* __restrict__ xib,
        const float* __restrict__ stats, const float* __restrict__ gamma,
        const float* __restrict__ beta, const int* __restrict__ seg,
        float* __restrict__ out) {
    __shared__ alignas(16) float scs[128];
    __shared__ alignas(16) float shs[128];
    if (threadIdx.x < 128) {
        int c = threadIdx.x;
        float mean = stats[c] * (1.0f / NSUP);
        float var = stats[128 + c] * (1.0f / NSUP) - mean * mean;
        float scale = gamma[c] / sqrtf(var + BN_EPS_C);
        scs[c] = scale;
        shs[c] = beta[c] - mean * scale;
    }
    __syncthreads();
    int t = blockIdx.x * 256 + threadIdx.x;     // NPIX*16
    int p = t >> 4, g = t & 15;
    int s = seg[p];
    int col = g * 8;
    uint4 v = *(const uint4*)(xib + (size_t)s * DD + col);
    float4 sc0 = *(const float4*)(scs + col), sc1 = *(const float4*)(scs + col + 4);
    float4 sh0 = *(const float4*)(shs + col), sh1 = *(const float4*)(shs + col + 4);
    float4 o0, o1;
    o0.x = lrelu(fmaf(bf2f_lo(v.x), sc0.x, sh0.x));
    o0.y = lrelu(fmaf(bf2f_hi(v.x), sc0.y, sh0.y));
    o0.z = lrelu(fmaf(bf2f_lo(v.y), sc0.z, sh0.z));
    o0.w = lrelu(fmaf(bf2f_hi(v.y), sc0.w, sh0.w));
    o1.x = lrelu(fmaf(bf2f_lo(v.z), sc1.x, sh1.x));
    o1.y = lrelu(fmaf(bf2f_hi(v.z), sc1.y, sh1.y));
    o1.z = lrelu(fmaf(bf2f_lo(v.w), sc1.z, sh1.z));
    o1.w = lrelu(fmaf(bf2f_hi(v.w), sc1.w, sh1.w));
    *(float4*)(out + (size_t)p * DD + col) = o0;
    *(float4*)(out + (size_t)p * DD + col + 4) = o1;
}

extern "C" void kernel_launch(void* const* d_in, const int* in_sizes, int n_in,
                              void* d_out, int out_size, void* d_ws, size_t ws_size,
                              hipStream_t stream) {
    const float* x     = (const float*)d_in[0];
    const float* W     = (const float*)d_in[1];
    const float* b     = (const float*)d_in[2];
    const float* gamma = (const float*)d_in[3];
    const float* beta  = (const float*)d_in[4];
    const float* ewt   = (const float*)d_in[5];
    const int*   seg   = (const int*)d_in[6];
    const int*   eidx  = (const int*)d_in[7];
    const int*   esrc  = eidx;
    const int*   edst  = eidx + NE;
    float* out = (float*)d_out;

    // d_out hosts transients zb | ya | yb (bf16 row-major, 38.4MB), dead before unpool.
    const size_t MAT = (size_t)NSUP * DD;
    unsigned short* zb = (unsigned short*)out;
    unsigned short* ya = zb + MAT;
    unsigned short* yb = ya + MAT;

    char* ws = (char*)d_ws;
    size_t off = 0;
    auto alloc = [&](size_t bytes) -> void* {
        void* p = ws + off;
        off = (off + bytes + 255) & ~(size_t)255;
        return p;
    };
    unsigned short* xib = (unsigned short*)alloc(sizeof(unsigned short) * MAT);  // 12.8 MB
    unsigned short* hb  = (unsigned short*)alloc(sizeof(unsigned short) * MAT);  // 12.8 MB
    unsigned short* Wtb = (unsigned short*)alloc(sizeof(unsigned short) * NL * DD * DD);
    int*   rowcnt  = (int*)alloc(sizeof(int) * CNT_CAP);
    int*   rowptr  = (int*)alloc(sizeof(int) * (NSUP + 1));
    int*   rowfill = (int*)alloc(sizeof(int) * NSUP);
    int*   pixcnt  = (int*)alloc(sizeof(int) * CNT_CAP);
    int*   pixptr  = (int*)alloc(sizeof(int) * (NSUP + 1));
    int*   pixfill = (int*)alloc(sizeof(int) * NSUP);
    int*   pixids  = (int*)alloc(sizeof(int) * NPIX);
    unsigned short* src16 = (unsigned short*)alloc(sizeof(unsigned short) * NEPAD4);
    float* ew      = (float*)alloc(sizeof(float) * NEPAD4);
    float* statsbf = (float*)alloc(sizeof(float) * NL * 256);    // per-layer raw sums

    hipMemsetAsync(rowcnt, 0, sizeof(int) * CNT_CAP, stream);
    hipMemsetAsync(rowfill, 0, sizeof(int) * NSUP, stream);
    hipMemsetAsync(pixcnt, 0, sizeof(int) * CNT_CAP, stream);
    hipMemsetAsync(pixfill, 0, sizeof(int) * NSUP, stream);
    hipMemsetAsync(src16, 0, sizeof(unsigned short) * NEPAD4, stream);  // pad -> src 0
    hipMemsetAsync(ew, 0, sizeof(float) * NEPAD4, stream);              // pad -> w 0.0
    hipMemsetAsync(statsbf, 0, sizeof(float) * NL * 256, stream);

    // W transpose+bf16 (all layers)
    wconv<<<(NL * DD * DD + 255) / 256, 256, 0, stream>>>(W, Wtb);

    // pixel CSR + pooling
    hist_k<<<(NPIX + 255) / 256, 256, 0, stream>>>(seg, pixcnt, NPIX);
    scan_rowptr<1><<<1, 1024, 0, stream>>>(pixcnt, pixptr);
    pix_scatter<<<(NPIX + 255) / 256, 256, 0, stream>>>(seg, pixptr, pixfill, pixids);
    pool_gather<<<NSUP / 8, 256, 0, stream>>>(x, pixptr, pixids, hb);

    // edge CSR by dst, rows padded to multiple of 4 (u16 src + f32 w)
    hist_k<<<(NE + 255) / 256, 256, 0, stream>>>(edst, rowcnt, NE);
    scan_rowptr<4><<<1, 1024, 0, stream>>>(rowcnt, rowptr);
    edge_scatter<<<(NE + 255) / 256, 256, 0, stream>>>(esrc, edst, ewt, rowptr, rowfill,
                                                       src16, ew);

    // 5 SFNet layers
    const int ggrid = (NSUP + 63) / 64;
    for (int i = 0; i < NL; ++i) {
        if (i == 0)
            gemm_mfma<0><<<ggrid, 128, 0, stream>>>(hb, nullptr, nullptr, nullptr,
                    Wtb + (size_t)i * DD * DD, b + i * DD, zb, ya);
        else
            gemm_mfma<1><<<ggrid, 128, 0, stream>>>(xib, statsbf + (i - 1) * 256,
                    gamma + (size_t)(i - 1) * DD, beta + (size_t)(i - 1) * DD,
                    Wtb + (size_t)i * DD * DD, b + i * DD, zb, ya);

        const unsigned short* ycur = ya;
        unsigned short* ynxt = yb;
        for (int t = 0; t < 4; ++t) {
            spmm_q<0><<<NSUP / 16, 256, 0, stream>>>(ycur, rowptr, src16, ew, zb,
                                                     nullptr, ynxt);
            const unsigned short* tmp = ycur;
            ycur = ynxt;
            ynxt = (unsigned short*)tmp;
        }
        spmm_q<1><<<NSUP / 16, 256, 0, stream>>>(ycur, rowptr, src16, ew, nullptr,
                                                 xib, nullptr);

        bn_stats<<<128, 256, 0, stream>>>(xib, statsbf + i * 256);
    }

    // final: BN+leaky fused into unpool (overwrites all of d_out)
    unpool_bn<<<NPIX * 16 / 256, 256, 0, stream>>>(xib, statsbf + (NL - 1) * 256,
            gamma + (size_t)(NL - 1) * DD, beta + (size_t)(NL - 1) * DD, seg, out);
}